// Round 7
// baseline (41.944 us; speedup 1.0000x reference)
//
#include <hip/hip_runtime.h>

// Conv2d 16->16, k=3, stride 1, pad 1, H=W=1024.
// Round 8: 100%-occupancy test -- 512-thread blocks, half staging jobs,
//          nt stores.
//   R7 post-mortem: residency is the ONLY lever that has moved BW
//   (12 -> 24 waves/CU gave 39.5 -> 37.1us); ILP pinning (R6), run length
//   (R5), schedules (R2-R4) all null. R7 was still VGPR/block-gated at
//   24 waves. This round: 512-thread blocks at TH=4 keep LDS at 25KB ->
//   4 blocks/CU x 8 waves = 32 waves/CU = 100% occupancy, REQUIRING
//   VGPR <= 64: staging jobs halved (8 planes/thread, 32 VGPR pinned
//   data; 408 half-jobs over 512 threads), asm pinning dropped (R6
//   proved it neutral), __launch_bounds__(512,8) caps the allocator.
//   Output (64MB, never reused) stored with __builtin_nontemporal_store
//   to bypass L2 -> full L2 for the input read stream (8.5MB column
//   stripe per XCD, halo reuse between vertical neighbors).
//   Geometry unchanged (verified R5-R7): TW=128, LDS [y][x][ci] bf16 w/
//   2-bit XOR swizzle on byte bits 4-5, K=160 = 5 x mfma_f32_16x16x32_bf16,
//   D[px][co] -> float4 stores, grid-x = 8 = #XCDs (column->XCD affinity).

#define H 1024
#define W 1024
#define HW (H * W)
#define TW 128
#define TH 4
#define LROWS 6              // TH + 2 halo rows
#define NQ 34                // float4-quads per halo row ([colbase-4, colbase+132))
#define NJOBS (LROWS * NQ)   // 204 full jobs -> 408 half jobs (<= 512 threads)
#define LCOLS 130            // staged cols: lx in [0, 130)
#define LPITCH (LCOLS * 32)  // 4160 B (32 B per col = 16 ci * 2 B)
#define LDS_BYTES (LROWS * LPITCH)   // 24960

typedef __bf16 bf16x8 __attribute__((ext_vector_type(8)));
typedef float f32x4 __attribute__((ext_vector_type(4)));
typedef unsigned short ushort8 __attribute__((ext_vector_type(8)));
typedef unsigned int uint4v __attribute__((ext_vector_type(4)));

__device__ __host__ inline unsigned short f2bf(float f) {
  unsigned u = __builtin_bit_cast(unsigned, f);
  return (unsigned short)((u + 0x7fffu + ((u >> 16) & 1u)) >> 16);  // RNE
}

// wA[p*512 + lane*8 + j]: weight fragment, col=co=lane&15, k=(lane>>4)*8+j;
// mfma p covers taps {2p, 2p+1}; tap = 2p + (k>>4), ci = k&15.
__global__ __launch_bounds__(256) void conv_prep(const float* __restrict__ w,
                                                 unsigned short* __restrict__ wA) {
  int i = blockIdx.x * 256 + threadIdx.x;
  if (i >= 5 * 64 * 8) return;
  int j = i & 7;
  int l = (i >> 3) & 63;
  int p = i >> 9;
  int k = (l >> 4) * 8 + j;
  int t = 2 * p + (k >> 4);
  int ci = k & 15;
  int co = l & 15;
  float v = (t <= 8) ? w[co * 144 + ci * 9 + t] : 0.f;  // w[co][ci][ky][kx], t=ky*3+kx
  wA[i] = f2bf(v);
}

__global__ __launch_bounds__(512, 8) void conv_mfma(
    const float* __restrict__ x, const unsigned short* __restrict__ wA,
    float* __restrict__ out) {
  __shared__ __align__(16) char lds[LDS_BYTES];

  const int tid  = threadIdx.x;
  const int lane = tid & 63;
  const int wave = tid >> 6;            // 0..7
  const int m = lane & 15;   // A row = pixel within 16-px group
  const int q = lane >> 4;   // k-quarter
  const int colbase = blockIdx.x * TW;
  const int rowbase = blockIdx.y * TH;

  // ---- stage: one HALF-job per thread (408 jobs = 4 cols x 8 channels) ----
  if (tid < 2 * NJOBS) {
    const int hf = tid & 1;            // plane half: channels hf*8 .. hf*8+7
    const int j  = tid >> 1;           // full-job id 0..203
    const int ly = j / NQ;             // 0..5
    const int qx = j - ly * NQ;        // 0..33
    const int gy = rowbase - 1 + ly;
    const float rowm = ((unsigned)gy < (unsigned)H) ? 1.f : 0.f;
    const int gyc  = gy < 0 ? 0 : (gy > H - 1 ? H - 1 : gy);
    const int gx0  = colbase - 4 + 4 * qx;
    const int gx0c = gx0 < 0 ? 0 : (gx0 > W - 4 ? W - 4 : gx0);
    const float* xb = x + hf * 8 * HW + gyc * W + gx0c;  // valid, 16-B aligned

    f32x4 L[8];
#pragma unroll
    for (int c = 0; c < 8; ++c)
      L[c] = *(const f32x4*)(xb + c * HW);

#pragma unroll
    for (int i = 0; i < 4; ++i) {
      const int gx = gx0 + i;
      const int lx = gx - (colbase - 1);
      if ((unsigned)lx < (unsigned)LCOLS) {
        const float fm = rowm * (((unsigned)gx < (unsigned)W) ? 1.f : 0.f);
        const int lb = (ly * LPITCH + lx * 32) ^ (((lx >> 2) & 3) << 4);
        uint4v d;
#pragma unroll
        for (int p = 0; p < 4; ++p) {
          const unsigned lo = f2bf(L[2 * p][i] * fm);
          const unsigned hi = f2bf(L[2 * p + 1][i] * fm);
          d[p] = lo | (hi << 16);
        }
        *(uint4v*)(lds + (lb ^ (hf << 4))) = d;
      }
    }
  }

  // ---- weight fragments: 5 x 16B uniform cached loads ----
  ushort8 wU[5];
#pragma unroll
  for (int p = 0; p < 5; ++p)
    wU[p] = *(const ushort8*)&wA[(p * 64 + lane) * 8];

  // ---- per-lane LDS read base addresses ----
  // wave w: output row r = w>>1, groups gbase = (w&1)*4 .. +3.
  const int r = wave >> 1;
  const int gbase = (wave & 1) * 4;
  int baseaddr[5];
#pragma unroll
  for (int p = 0; p < 5; ++p) {
    int t = 2 * p + (q >> 1);
    int ky = 0, kx = 0;
    if (t <= 8) { ky = t / 3; kx = t - ky * 3; }  // t==9: valid addr, zero weights
    int col = m + kx;
    int b = ky * LPITCH + col * 32 + (q & 1) * 16;
    b ^= ((col >> 2) & 3) << 4;
    baseaddr[p] = b + r * LPITCH;      // r*LPITCH has no bits <6: swizzle safe
  }

  __syncthreads();

  // ---- compute: 4 groups of 16 px for row (rowbase + r) ----
#pragma unroll
  for (int g = 0; g < 4; ++g) {
    f32x4 acc = {0.f, 0.f, 0.f, 0.f};
#pragma unroll
    for (int p = 0; p < 5; ++p) {
      // (gbase+g)*512 touches only byte bits >=9: swizzle-safe offset.
      ushort8 bU = *(const ushort8*)(lds + (baseaddr[p] + (gbase + g) * 512));
      acc = __builtin_amdgcn_mfma_f32_16x16x32_bf16(
          __builtin_bit_cast(bf16x8, bU),       // A = pixels
          __builtin_bit_cast(bf16x8, wU[p]),    // B = weights
          acc, 0, 0, 0);
    }
    // D: col = lane&15 = c_out, row = q*4+j = pixel -> float4 nt-store of
    // 4 consecutive pixels for one channel (output never reused: bypass L2).
    const int y  = rowbase + r;
    const int x0 = colbase + (gbase + g) * 16 + q * 4;
    __builtin_nontemporal_store(acc, (f32x4*)(out + m * HW + y * W + x0));
  }
}

extern "C" void kernel_launch(void* const* d_in, const int* in_sizes, int n_in,
                              void* d_out, int out_size, void* d_ws, size_t ws_size,
                              hipStream_t stream) {
  const float* x = (const float*)d_in[0];            // (1,16,1024,1024) fp32
  const float* w = (const float*)d_in[1];            // (16,16,3,3) fp32
  float* out = (float*)d_out;                        // (16,1024,1024) fp32
  unsigned short* wA = (unsigned short*)d_ws;        // 2560 ushorts = 5120 B

  conv_prep<<<10, 256, 0, stream>>>(w, wA);

  dim3 grid(W / TW, H / TH);                         // 8 x 256 = 2048 blocks
  conv_mfma<<<grid, 512, 0, stream>>>(x, wA, out);
}

// Round 8
// 41.285 us; speedup vs baseline: 1.0160x; 1.0160x over previous
//
#include <hip/hip_runtime.h>

// Conv2d 16->16, k=3, stride 1, pad 1, H=W=1024.
// Round 9: plane-major staging (DRAM page-queue locality test).
//   R8 post-mortem: nt stores inflated WRITE 66->85MB (partial-line writes
//   without L2 combining) -> reverted; 512-thr blocks gave no occupancy.
//   Eight-round tally: bytes near-minimal, BW pinned 2.7-3.7 TB/s across
//   ILP 4->16, run 256->544B, 4 schedules; only residency moved BW. The
//   never-varied invariant: every thread loads 16 planes 4MB apart, so
//   same-page requests reach the DRAM queue from different CUs at
//   uncorrelated times -> no page-hit batching. The 6.3 TB/s copy issues
//   same-page requests back-to-back per wave. Fix (single variable vs R7):
//   wave w stages ci-half (w&1) over quad-half (w>>1); per thread 8 planes
//   x 2 chunks, issued PLANE-MAJOR with sched_barrier(0) separators so
//   each plane gets 2 back-to-back 1KB-footprint instrs walking forward.
//   ds_write_b128 path, LDS layout/swizzle, compute phase identical to R7
//   (TH=4, TW=128, 25KB LDS, 6 blocks/CU = 24 waves, plain f32x4 stores).

#define H 1024
#define W 1024
#define HW (H * W)
#define TW 128
#define TH 4
#define LROWS 6              // TH + 2 halo rows
#define NQ 34                // float4-quads per halo row ([colbase-4, colbase+132))
#define NJOBS (LROWS * NQ)   // 204 quads
#define NHALF 102            // quads per quad-half (2 chunks: 64 + 38)
#define LCOLS 130            // staged cols: lx in [0, 130)
#define LPITCH (LCOLS * 32)  // 4160 B (32 B per col = 16 ci * 2 B)
#define LDS_BYTES (LROWS * LPITCH)   // 24960

typedef __bf16 bf16x8 __attribute__((ext_vector_type(8)));
typedef float f32x4 __attribute__((ext_vector_type(4)));
typedef unsigned short ushort8 __attribute__((ext_vector_type(8)));
typedef unsigned int uint4v __attribute__((ext_vector_type(4)));

__device__ __host__ inline unsigned short f2bf(float f) {
  unsigned u = __builtin_bit_cast(unsigned, f);
  return (unsigned short)((u + 0x7fffu + ((u >> 16) & 1u)) >> 16);  // RNE
}

// wA[p*512 + lane*8 + j]: weight fragment, col=co=lane&15, k=(lane>>4)*8+j;
// mfma p covers taps {2p, 2p+1}; tap = 2p + (k>>4), ci = k&15.
__global__ __launch_bounds__(256) void conv_prep(const float* __restrict__ w,
                                                 unsigned short* __restrict__ wA) {
  int i = blockIdx.x * 256 + threadIdx.x;
  if (i >= 5 * 64 * 8) return;
  int j = i & 7;
  int l = (i >> 3) & 63;
  int p = i >> 9;
  int k = (l >> 4) * 8 + j;
  int t = 2 * p + (k >> 4);
  int ci = k & 15;
  int co = l & 15;
  float v = (t <= 8) ? w[co * 144 + ci * 9 + t] : 0.f;  // w[co][ci][ky][kx], t=ky*3+kx
  wA[i] = f2bf(v);
}

__global__ __launch_bounds__(256, 6) void conv_mfma(
    const float* __restrict__ x, const unsigned short* __restrict__ wA,
    float* __restrict__ out) {
  __shared__ __align__(16) char lds[LDS_BYTES];

  const int tid  = threadIdx.x;
  const int lane = tid & 63;
  const int wave = tid >> 6;
  const int m = lane & 15;   // A row = pixel within 16-px group
  const int q = lane >> 4;   // k-quarter
  const int colbase = blockIdx.x * TW;
  const int rowbase = blockIdx.y * TH;

  // ---- plane-major staging ----
  // wave w: planes (w&1)*8..+7 over quads [(w>>1)*102, +102).
  const int phalf = wave & 1;        // ci half (LDS byte offset phalf*16)
  const int qhalf = wave >> 1;       // quad half
  int lyk[2], gx0k[2];
  float rowmk[2];
  unsigned voffk[2];
  bool actk[2];
#pragma unroll
  for (int k = 0; k < 2; ++k) {
    const int jj = k * 64 + lane;
    actk[k] = jj < NHALF;
    const int j = qhalf * NHALF + (actk[k] ? jj : NHALF - 1);
    const int ly = j / NQ, qx = j - ly * NQ;
    lyk[k] = ly;
    const int gy = rowbase - 1 + ly;
    rowmk[k] = ((unsigned)gy < (unsigned)H) ? 1.f : 0.f;
    const int gyc = gy < 0 ? 0 : (gy > H - 1 ? H - 1 : gy);
    const int gx0 = colbase - 4 + 4 * qx;
    gx0k[k] = gx0;
    const int gx0c = gx0 < 0 ? 0 : (gx0 > W - 4 ? W - 4 : gx0);
    voffk[k] = (unsigned)(gyc * W + gx0c);      // elements; valid & 16-B aligned
  }

  // 8 planes x 2 chunks, plane-major issue order pinned by sched_barrier(0):
  // per plane, 2 back-to-back wave-instrs (~1 KB footprint each) walking
  // forward -> same-page requests adjacent in the DRAM queue.
  f32x4 L[8][2];
#pragma unroll
  for (int c = 0; c < 8; ++c) {
    const float* xp = x + (phalf * 8 + c) * HW;
    L[c][0] = *(const f32x4*)(xp + voffk[0]);
    L[c][1] = *(const f32x4*)(xp + voffk[1]);
    __builtin_amdgcn_sched_barrier(0);
  }

  // pack fp32 -> bf16 pairs; one ds_write_b128 (8 ci) per (chunk, col).
#pragma unroll
  for (int k = 0; k < 2; ++k) {
    if (actk[k]) {
#pragma unroll
      for (int i = 0; i < 4; ++i) {
        const int gx = gx0k[k] + i;
        const int lx = gx - (colbase - 1);
        if ((unsigned)lx < (unsigned)LCOLS) {
          const float fm = rowmk[k] * (((unsigned)gx < (unsigned)W) ? 1.f : 0.f);
          uint4v d;
#pragma unroll
          for (int p = 0; p < 4; ++p) {
            const unsigned lo = f2bf(L[2 * p][k][i] * fm);
            const unsigned hi = f2bf(L[2 * p + 1][k][i] * fm);
            d[p] = lo | (hi << 16);
          }
          const int b =
              (lyk[k] * LPITCH + lx * 32 + phalf * 16) ^ (((lx >> 2) & 3) << 4);
          *(uint4v*)(lds + b) = d;
        }
      }
    }
  }
  __builtin_amdgcn_sched_barrier(0);   // keep weight loads out of staging

  // ---- weight fragments: 5 x 16B uniform cached loads ----
  ushort8 wU[5];
#pragma unroll
  for (int p = 0; p < 5; ++p)
    wU[p] = *(const ushort8*)&wA[(p * 64 + lane) * 8];

  // ---- per-lane LDS read base addresses (wave owns row rowbase+wave) ----
  int baseaddr[5];
#pragma unroll
  for (int p = 0; p < 5; ++p) {
    int t = 2 * p + (q >> 1);
    int ky = 0, kx = 0;
    if (t <= 8) { ky = t / 3; kx = t - ky * 3; }  // t==9: valid addr, zero weights
    int col = m + kx;
    int b = ky * LPITCH + col * 32 + (q & 1) * 16;
    b ^= ((col >> 2) & 3) << 4;
    baseaddr[p] = b + wave * LPITCH;
  }

  __syncthreads();

  // ---- compute: wave -> row (rowbase+wave), 8 groups of 16 px ----
#pragma unroll
  for (int g = 0; g < 8; ++g) {
    f32x4 acc = {0.f, 0.f, 0.f, 0.f};
#pragma unroll
    for (int p = 0; p < 5; ++p) {
      ushort8 bU = *(const ushort8*)(lds + (baseaddr[p] + g * 512));
      acc = __builtin_amdgcn_mfma_f32_16x16x32_bf16(
          __builtin_bit_cast(bf16x8, bU),       // A = pixels
          __builtin_bit_cast(bf16x8, wU[p]),    // B = weights
          acc, 0, 0, 0);
    }
    // D: col = lane&15 = c_out, row = q*4+j = pixel -> float4 store of 4
    // consecutive pixels for one channel.
    const int y  = rowbase + wave;
    const int x0 = colbase + g * 16 + q * 4;
    *(f32x4*)(out + m * HW + y * W + x0) = acc;
  }
}

extern "C" void kernel_launch(void* const* d_in, const int* in_sizes, int n_in,
                              void* d_out, int out_size, void* d_ws, size_t ws_size,
                              hipStream_t stream) {
  const float* x = (const float*)d_in[0];            // (1,16,1024,1024) fp32
  const float* w = (const float*)d_in[1];            // (16,16,3,3) fp32
  float* out = (float*)d_out;                        // (16,1024,1024) fp32
  unsigned short* wA = (unsigned short*)d_ws;        // 2560 ushorts = 5120 B

  conv_prep<<<10, 256, 0, stream>>>(w, wA);

  dim3 grid(W / TW, H / TH);                         // 8 x 256 = 2048 blocks
  conv_mfma<<<grid, 256, 0, stream>>>(x, wA, out);
}

// Round 9
// 41.006 us; speedup vs baseline: 1.0229x; 1.0068x over previous
//
#include <hip/hip_runtime.h>

// Conv2d 16->16, k=3, stride 1, pad 1, H=W=1024.
// Round 10: full-row-band rolling kernel -- page-length HBM runs.
//   Nine-round ledger: bytes minimal (FETCH 51-56MB, WRITE 66MB); BW pinned
//   2.7-3.7 TB/s across ILP 4->16, 4 schedules, 7->24 waves/CU, runs
//   256->544B. Never tested: runs >= DRAM page. fillBuffer (inf runs) 6.6,
//   copy (long runs) 6.3, all sub-page tiles ~3.4 TB/s. TW-tiles can't make
//   page runs; the tile shape must change. This round: TW=512 half-row x
//   4-row band, marching down rows with a ring of 4 LDS row-slots (16.4KB
//   each, 65.8KB total -> 2 blocks/CU, 16 waves). Per step: stage ONE input
//   row (16 planes x ~2KB contiguous runs), compute one output row (2KB
//   store runs per plane), ring reuse kills intra-band halo re-reads.
//   Loads for step s+1 issued before compute(s); ONE raw lgkm+s_barrier
//   per step (ring-4 proof: pack slot (s+2)&3 disjoint from compute(s-1)
//   slots {s-1,s,s+1}&3); loads stay in flight across barriers (R4 mech).
//   XCD banding: bid&7 = XCD owns 32 vertically-contiguous bands -> seam
//   halo rows shared through that XCD's L2.
//   Compute machinery = R7 verbatim: LDS [x][ci] bf16, 32B/col, XOR swizzle
//   ((col>>2)&3)<<4 on bits 4-5, K=160 = 5 x mfma_f32_16x16x32_bf16,
//   D[px][co] -> float4 stores, weights pre-shuffled by prep kernel.

#define H 1024
#define W 1024
#define HW (H * W)
#define TW 512
#define RPB 4                // rows per band
#define NQ 130               // float4-quads per row ([colbase-4, colbase+516))
#define NJ 260               // staging jobs = NQ * 2 ci-halves
#define LCOLS 514            // staged cols: lx in [0, 514)
#define PITCH (LCOLS * 32)   // 16448 B per row-slot (bits 0-5 zero: swizzle-safe)
#define NSLOT 4
#define LDS_BYTES (NSLOT * PITCH)   // 65792

typedef __bf16 bf16x8 __attribute__((ext_vector_type(8)));
typedef float f32x4 __attribute__((ext_vector_type(4)));
typedef unsigned short ushort8 __attribute__((ext_vector_type(8)));
typedef unsigned int uint4v __attribute__((ext_vector_type(4)));

__device__ __host__ inline unsigned short f2bf(float f) {
  unsigned u = __builtin_bit_cast(unsigned, f);
  return (unsigned short)((u + 0x7fffu + ((u >> 16) & 1u)) >> 16);  // RNE
}

// wA[p*512 + lane*8 + j]: weight fragment, col=co=lane&15, k=(lane>>4)*8+j;
// mfma p covers taps {2p, 2p+1}; tap = 2p + (k>>4), ci = k&15.
__global__ __launch_bounds__(256) void conv_prep(const float* __restrict__ w,
                                                 unsigned short* __restrict__ wA) {
  int i = blockIdx.x * 256 + threadIdx.x;
  if (i >= 5 * 64 * 8) return;
  int j = i & 7;
  int l = (i >> 3) & 63;
  int p = i >> 9;
  int k = (l >> 4) * 8 + j;
  int t = 2 * p + (k >> 4);
  int ci = k & 15;
  int co = l & 15;
  float v = (t <= 8) ? w[co * 144 + ci * 9 + t] : 0.f;  // w[co][ci][ky][kx], t=ky*3+kx
  wA[i] = f2bf(v);
}

__global__ __launch_bounds__(512, 4) void conv_mfma(
    const float* __restrict__ x, const unsigned short* __restrict__ wA,
    float* __restrict__ out) {
  __shared__ __align__(16) char lds[LDS_BYTES];

  const int tid  = threadIdx.x;
  const int lane = tid & 63;
  const int wave = tid >> 6;           // 0..7
  const int m = lane & 15;   // A row = pixel within 16-px group; D col = co
  const int q = lane >> 4;   // k-quarter

  // ---- block -> (column half, band) with XCD-contiguous vertical bands ----
  const int bid = blockIdx.x;          // 0..511
  const int xcd = bid & 7;
  const int u   = bid >> 3;            // 0..63
  const int cb  = u & 1;
  const int r0  = (xcd * 32 + (u >> 1)) * RPB;   // band start row
  const int colbase = cb * TW;

  // ---- staging geometry (row-invariant): job = 4 cols x 8 planes ----
  const bool st = tid < NJ;
  int hf = 0, gx0 = 0;
  const float* xcol = x;
  if (st) {
    hf  = tid & 1;                     // ci half
    const int qx = tid >> 1;           // 0..129
    gx0 = colbase - 4 + 4 * qx;
    const int gx0c = gx0 < 0 ? 0 : (gx0 > W - 4 ? W - 4 : gx0);
    xcol = x + hf * 8 * HW + gx0c;     // plane-half + column base (valid, 16B-aligned)
  }

  f32x4 LA[8], LB[8];
  float rmA, rmB;

#define ISSUE(Lr, rm, y)                                                    \
  {                                                                         \
    const int gy = (y);                                                     \
    rm = ((unsigned)gy < (unsigned)H) ? 1.f : 0.f;                          \
    const int gyc = gy < 0 ? 0 : (gy > H - 1 ? H - 1 : gy);                 \
    const float* xb = xcol + gyc * W;                                       \
    if (st) {                                                               \
      _Pragma("unroll") for (int c = 0; c < 8; ++c)                         \
          Lr[c] = *(const f32x4*)(xb + c * HW);                             \
    }                                                                       \
  }

#define PACK(Lr, rm, slot)                                                  \
  if (st) {                                                                 \
    char* const sb = lds + (slot) * PITCH;                                  \
    _Pragma("unroll") for (int i = 0; i < 4; ++i) {                         \
      const int gx = gx0 + i;                                               \
      const int lx = gx - (colbase - 1);                                    \
      if ((unsigned)lx < (unsigned)LCOLS) {                                 \
        const float fm = rm * (((unsigned)gx < (unsigned)W) ? 1.f : 0.f);   \
        uint4v d;                                                           \
        _Pragma("unroll") for (int p = 0; p < 4; ++p) {                     \
          const unsigned lo = f2bf(Lr[2 * p][i] * fm);                      \
          const unsigned hi = f2bf(Lr[2 * p + 1][i] * fm);                  \
          d[p] = lo | (hi << 16);                                           \
        }                                                                   \
        const int b = (lx * 32 + hf * 16) ^ (((lx >> 2) & 3) << 4);         \
        *(uint4v*)(sb + b) = d;                                             \
      }                                                                     \
    }                                                                       \
  }

#define BAR()                                                \
  asm volatile("s_waitcnt lgkmcnt(0)" ::: "memory");         \
  asm volatile("s_barrier" ::: "memory")

  // ---- weight fragments: 5 x 16B uniform cached loads ----
  ushort8 wU[5];
#pragma unroll
  for (int p = 0; p < 5; ++p)
    wU[p] = *(const ushort8*)&wA[(p * 64 + lane) * 8];

  // ---- per-lane LDS read offsets (slot-relative) ----
  int roff[5], kyv[5];
#pragma unroll
  for (int p = 0; p < 5; ++p) {
    int t = 2 * p + (q >> 1);
    int ky = 0, kx = 0;
    if (t <= 8) { ky = t / 3; kx = t - ky * 3; }  // t==9: valid addr, zero weights
    const int col = m + kx;
    roff[p] = (col * 32 + (q & 1) * 16) ^ (((col >> 2) & 3) << 4);
    kyv[p] = ky;
  }

  // Input row r0-1+rel lives in ring slot rel&3. Compute(s) reads slots
  // {s, s+1, s+2}&3; pack at step s fills slot (s+2)&3 (disjoint from
  // compute(s-1)'s slots) -> ONE barrier per step is race-free.
#define COMPUTE(S)                                                          \
  {                                                                         \
    const int y = r0 + (S);                                                 \
    float* const orow = out + m * HW + y * W + colbase + q * 4;             \
    _Pragma("unroll") for (int gg = 0; gg < 4; ++gg) {                      \
      f32x4 acc = {0.f, 0.f, 0.f, 0.f};                                     \
      _Pragma("unroll") for (int p = 0; p < 5; ++p) {                       \
        const int slot = ((S) + kyv[p]) & 3;                                \
        const ushort8 bU = *(const ushort8*)(lds + slot * PITCH + roff[p] + \
                                             (wave * 4 + gg) * 512);        \
        acc = __builtin_amdgcn_mfma_f32_16x16x32_bf16(                      \
            __builtin_bit_cast(bf16x8, bU),   /* A = pixels  */             \
            __builtin_bit_cast(bf16x8, wU[p]),/* B = weights */             \
            acc, 0, 0, 0);                                                  \
      }                                                                     \
      *(f32x4*)(orow + (wave * 4 + gg) * 16) = acc;                         \
    }                                                                       \
  }

  // ---- prologue: rows r0-1, r0 staged; r0+1 in flight ----
  ISSUE(LA, rmA, r0 - 1);
  ISSUE(LB, rmB, r0);
  PACK(LA, rmA, 0);
  PACK(LB, rmB, 1);
  ISSUE(LA, rmA, r0 + 1);

  // ---- steps: pack(s) -> issue(s+1) -> barrier -> compute(s) ----
  PACK(LA, rmA, 2); ISSUE(LB, rmB, r0 + 2);
  BAR(); COMPUTE(0);
  PACK(LB, rmB, 3); ISSUE(LA, rmA, r0 + 3);
  BAR(); COMPUTE(1);
  PACK(LA, rmA, 0); ISSUE(LB, rmB, r0 + 4);
  BAR(); COMPUTE(2);
  PACK(LB, rmB, 1);
  BAR(); COMPUTE(3);

#undef ISSUE
#undef PACK
#undef BAR
#undef COMPUTE
}

extern "C" void kernel_launch(void* const* d_in, const int* in_sizes, int n_in,
                              void* d_out, int out_size, void* d_ws, size_t ws_size,
                              hipStream_t stream) {
  const float* x = (const float*)d_in[0];            // (1,16,1024,1024) fp32
  const float* w = (const float*)d_in[1];            // (16,16,3,3) fp32
  float* out = (float*)d_out;                        // (16,1024,1024) fp32
  unsigned short* wA = (unsigned short*)d_ws;        // 2560 ushorts = 5120 B

  conv_prep<<<10, 256, 0, stream>>>(w, wA);

  conv_mfma<<<dim3(512), 512, 0, stream>>>(x, wA, out);
}